// Round 3
// baseline (1263.125 us; speedup 1.0000x reference)
//
#include <hip/hip_runtime.h>
#include <hip/hip_bf16.h>
#include <math.h>

#define U_N   8192
#define I_N   16384
#define D_N   64
#define OUT_N 64
#define BN    32          // items per wave-iteration
#define PL_ST 40          // P round-trip stride in halves: 32 + 8 pad

typedef _Float16       half8  __attribute__((ext_vector_type(8)));
typedef short          bf16x8 __attribute__((ext_vector_type(8)));
typedef float          f32x4  __attribute__((ext_vector_type(4)));

static __device__ __forceinline__ unsigned short f2bf(float f) {
    union { __hip_bfloat16 h; unsigned short u; } cv;
    cv.h = __float2bfloat16(f);
    return cv.u;
}

// ---------------------------------------------------------------------------
// Prep: item_emb fp32 -> itemH f16 [item][dim] (S B-frags) and
//       itemT bf16 [dim][item] (PV B-frags). 4 MB total, L2-resident after.
// ---------------------------------------------------------------------------
__global__ __launch_bounds__(256)
void prep_items(const float* __restrict__ item,
                _Float16* __restrict__ itemH,
                unsigned short* __restrict__ itemT)
{
    const int i = blockIdx.x * 256 + threadIdx.x;      // item index
    const float* src = item + (size_t)i * D_N;
    f32x4 v[16];
    #pragma unroll
    for (int j = 0; j < 16; ++j) v[j] = *(const f32x4*)(src + 4 * j);

    #pragma unroll
    for (int j = 0; j < 8; ++j) {                      // f16 row, 8x half8
        half8 h;
        #pragma unroll
        for (int k = 0; k < 4; ++k) { h[k] = (_Float16)v[2*j][k]; h[4+k] = (_Float16)v[2*j+1][k]; }
        *(half8*)&itemH[(size_t)i * D_N + 8 * j] = h;
    }
    #pragma unroll
    for (int d = 0; d < 64; ++d)                       // bf16 transpose (coalesced per d)
        itemT[(size_t)d * I_N + i] = f2bf(v[d >> 2][d & 3]);
}

// ---------------------------------------------------------------------------
// Main: barrier-free flash loop. Wave owns 16 users x BN=32 items/iter.
// B-fragments read directly from global (itemH/itemT), adj+S-frags double-
// buffered one iteration ahead. Max-free softmax (scores N(0,64): exp safe
// in fp32/bf16). Only LDS use is the per-wave P C->A layout round-trip.
// ---------------------------------------------------------------------------
__global__ __launch_bounds__(256, 4)
void atten_main(const float* __restrict__ user_emb,
                const _Float16* __restrict__ itemH,
                const unsigned short* __restrict__ itemT,
                const int*   __restrict__ adj,
                float* __restrict__ wsO,
                float* __restrict__ wsL,
                int items_per_ch, int iters)
{
    __shared__ unsigned short Pl[4][16 * PL_ST];   // per-wave P round-trip, bf16

    const int ch   = blockIdx.x;
    const int ub   = blockIdx.y;
    const int t    = threadIdx.x;
    const int w    = t >> 6;
    const int lane = t & 63;
    const int c    = lane & 15;     // MFMA column lane
    const int q    = lane >> 4;     // quad 0..3

    const int urow0  = ub * 64 + w * 16;
    const int ibase0 = ch * items_per_ch;

    // ---- persistent user A-fragments (f16): A[m=c][k=ks*32+q*8+j] ----
    half8 ufrag[2];
    {
        const float* up = user_emb + (size_t)(urow0 + c) * D_N + q * 8;
        #pragma unroll
        for (int ks = 0; ks < 2; ++ks) {
            f32x4 a = *(const f32x4*)(up + ks * 32);
            f32x4 b = *(const f32x4*)(up + ks * 32 + 4);
            half8 h;
            #pragma unroll
            for (int j = 0; j < 4; ++j) { h[j] = (_Float16)a[j]; h[4 + j] = (_Float16)b[j]; }
            ufrag[ks] = h;
        }
    }

    f32x4 O[4];
    #pragma unroll
    for (int nt = 0; nt < 4; ++nt) O[nt] = (f32x4){0.f, 0.f, 0.f, 0.f};
    float l_r[4] = {0.f, 0.f, 0.f, 0.f};

    // ---- base pointers ----
    const int*      adjb = adj   + (size_t)(urow0 + 4 * q) * I_N + ibase0 + c;
    const _Float16* sbb  = itemH + (size_t)(ibase0 + c) * D_N + q * 8;
    const unsigned short* pvb = itemT + (size_t)c * I_N + ibase0 + q * 8;

    int   adj_pf[2][8];
    half8 sb_pf[2][4];

    // ---- prefetch iter 0 into buffer 0 ----
    #pragma unroll
    for (int r = 0; r < 4; ++r)
        #pragma unroll
        for (int n2 = 0; n2 < 2; ++n2)
            adj_pf[0][r * 2 + n2] = adjb[(size_t)r * I_N + n2 * 16];
    #pragma unroll
    for (int n2 = 0; n2 < 2; ++n2)
        #pragma unroll
        for (int ks = 0; ks < 2; ++ks)
            sb_pf[0][n2 * 2 + ks] = *(const half8*)&sbb[(size_t)(n2 * 16) * D_N + ks * 32];

    for (int it = 0; it < iters; ++it) {
        const int    b   = it & 1;
        const size_t off = (size_t)it * BN;

        // ---- next-iter prefetch into the other buffer (no WAR on current) ----
        if (it + 1 < iters) {
            const size_t noff = off + BN;
            #pragma unroll
            for (int r = 0; r < 4; ++r)
                #pragma unroll
                for (int n2 = 0; n2 < 2; ++n2)
                    adj_pf[b ^ 1][r * 2 + n2] = adjb[(size_t)r * I_N + noff + n2 * 16];
            #pragma unroll
            for (int n2 = 0; n2 < 2; ++n2)
                #pragma unroll
                for (int ks = 0; ks < 2; ++ks)
                    sb_pf[b ^ 1][n2 * 2 + ks] =
                        *(const half8*)&sbb[(noff + n2 * 16) * D_N + ks * 32];
        }

        // ---- current-iter PV B-frags from itemT (L2-resident), used last ----
        bf16x8 pv[4];
        #pragma unroll
        for (int nt = 0; nt < 4; ++nt)
            pv[nt] = *(const bf16x8*)&pvb[(size_t)nt * 16 * I_N + off];

        // ---- adj mask (bit r*2+n2) ----
        unsigned mask = 0;
        #pragma unroll
        for (int k = 0; k < 8; ++k) mask |= (adj_pf[b][k] != 0 ? 1u : 0u) << k;

        // ---- S = U * I^T  (16 users x 32 items, f16 MFMA) ----
        f32x4 S[2];
        #pragma unroll
        for (int n2 = 0; n2 < 2; ++n2) {
            f32x4 acc = (f32x4){0.f, 0.f, 0.f, 0.f};
            #pragma unroll
            for (int ks = 0; ks < 2; ++ks)
                acc = __builtin_amdgcn_mfma_f32_16x16x32_f16(ufrag[ks], sb_pf[b][n2 * 2 + ks],
                                                             acc, 0, 0, 0);
            S[n2] = acc;
        }

        // ---- mask + exp (un-normalized numerator), partial l ----
        #pragma unroll
        for (int r = 0; r < 4; ++r)
            #pragma unroll
            for (int n2 = 0; n2 < 2; ++n2) {
                const float s = ((mask >> (r * 2 + n2)) & 1u) ? S[n2][r] : 0.0f;
                const float p = __expf(s);
                S[n2][r] = p;
                l_r[r] += p;
            }

        // ---- P: C-layout -> LDS (bf16) -> A-layout (per-wave, no barrier) ----
        #pragma unroll
        for (int r = 0; r < 4; ++r)
            #pragma unroll
            for (int n2 = 0; n2 < 2; ++n2)
                Pl[w][(4 * q + r) * PL_ST + n2 * 16 + c] = f2bf(S[n2][r]);

        bf16x8 pfrag = *(const bf16x8*)&Pl[w][c * PL_ST + q * 8];

        // ---- O += P * V (bf16 MFMA, k=32 items) ----
        #pragma unroll
        for (int nt = 0; nt < 4; ++nt)
            O[nt] = __builtin_amdgcn_mfma_f32_16x16x32_bf16(pfrag, pv[nt], O[nt], 0, 0, 0);
    }

    // ---- one-time l reduction across the 16 lanes of each quad-row ----
    #pragma unroll
    for (int r = 0; r < 4; ++r) {
        float v = l_r[r];
        #pragma unroll
        for (int offx = 1; offx < 16; offx <<= 1) v += __shfl_xor(v, offx);
        l_r[r] = v;
    }

    // ---- write chunk partials ----
    #pragma unroll
    for (int r = 0; r < 4; ++r) {
        const int u = urow0 + 4 * q + r;
        float* dst = wsO + ((size_t)ch * U_N + u) * D_N;
        #pragma unroll
        for (int nt = 0; nt < 4; ++nt)
            dst[16 * nt + c] = O[nt][r];
    }
    if (c == 0) {
        #pragma unroll
        for (int r = 0; r < 4; ++r)
            wsL[(size_t)ch * U_N + urow0 + 4 * q + r] = l_r[r];
    }
}

// ---------------------------------------------------------------------------
// Combine: sum chunk partials, normalize by total l, project by attention_weight.
// ---------------------------------------------------------------------------
__global__ __launch_bounds__(256)
void atten_combine(const float* __restrict__ wsO,
                   const float* __restrict__ wsL,
                   const float* __restrict__ attw,
                   float* __restrict__ out,
                   int nch)
{
    __shared__ float inv[64];
    __shared__ float agg[64][68];
    __shared__ float Wl[64][68];

    const int t  = threadIdx.x;
    const int u0 = blockIdx.x * 64;

    {   // stage W
        const int d = t >> 2, o0 = (t & 3) * 16;
        const float* src = attw + d * OUT_N + o0;
        #pragma unroll
        for (int j = 0; j < 4; ++j)
            *(f32x4*)&Wl[d][o0 + 4 * j] = *(const f32x4*)(src + 4 * j);
    }
    if (t < 64) {
        float L = 0.f;
        for (int cc = 0; cc < nch; ++cc) L += wsL[(size_t)cc * U_N + u0 + t];
        inv[t] = 1.0f / L;
    }
    __syncthreads();

    {   // agg[u][d] = (sum_c O_c[u][d]) / L[u]
        const int ul = t >> 2, d0 = (t & 3) * 16;
        const int u = u0 + ul;
        f32x4 a4[4];
        #pragma unroll
        for (int j = 0; j < 4; ++j) a4[j] = (f32x4){0.f, 0.f, 0.f, 0.f};
        for (int cc = 0; cc < nch; ++cc) {
            const float* src = wsO + ((size_t)cc * U_N + u) * D_N + d0;
            #pragma unroll
            for (int j = 0; j < 4; ++j) a4[j] += *(const f32x4*)(src + 4 * j);
        }
        const float s = inv[ul];
        #pragma unroll
        for (int j = 0; j < 4; ++j)
            *(f32x4*)&agg[ul][d0 + 4 * j] = a4[j] * s;
    }
    __syncthreads();

    {   // out[u][o] = sum_d agg[u][d] * W[d][o]
        const int ul = t >> 2, o0 = (t & 3) * 16;
        f32x4 acc[4];
        #pragma unroll
        for (int j = 0; j < 4; ++j) acc[j] = (f32x4){0.f, 0.f, 0.f, 0.f};
        for (int d = 0; d < 64; ++d) {
            const float av = agg[ul][d];
            #pragma unroll
            for (int j = 0; j < 4; ++j) {
                f32x4 wv = *(const f32x4*)&Wl[d][o0 + 4 * j];
                acc[j] += wv * av;
            }
        }
        float* dst = out + (size_t)(u0 + ul) * OUT_N + o0;
        #pragma unroll
        for (int j = 0; j < 4; ++j)
            *(f32x4*)(dst + 4 * j) = acc[j];
    }
}

// ---------------------------------------------------------------------------
extern "C" void kernel_launch(void* const* d_in, const int* in_sizes, int n_in,
                              void* d_out, int out_size, void* d_ws, size_t ws_size,
                              hipStream_t stream)
{
    const float* user_emb = (const float*)d_in[0];
    const float* item_emb = (const float*)d_in[1];
    const float* attw     = (const float*)d_in[2];
    const int*   adj      = (const int*)d_in[3];
    float* out = (float*)d_out;

    int nch = 8;

    // ws layout (offsets fixed for max nch=8): wsO | wsL | itemH | itemT
    float*          wsO   = (float*)d_ws;
    float*          wsL   = wsO + (size_t)8 * U_N * D_N;
    _Float16*       itemH = (_Float16*)(wsL + (size_t)8 * U_N);
    unsigned short* itemT = (unsigned short*)(itemH + (size_t)I_N * D_N);

    const int items_per_ch = I_N / nch;
    const int iters = items_per_ch / BN;

    prep_items<<<dim3(I_N / 256), 256, 0, stream>>>(item_emb, itemH, itemT);
    atten_main<<<dim3(nch, U_N / 64), 256, 0, stream>>>(user_emb, itemH, itemT, adj,
                                                        wsO, wsL, items_per_ch, iters);
    atten_combine<<<dim3(U_N / 64), 256, 0, stream>>>(wsO, wsL, attw, out, nch);
}

// Round 4
// 1134.909 us; speedup vs baseline: 1.1130x; 1.1130x over previous
//
#include <hip/hip_runtime.h>
#include <hip/hip_bf16.h>
#include <math.h>

#define U_N   8192
#define I_N   16384
#define D_N   64
#define OUT_N 64
#define BN    32          // items per wave-iteration
#define PL_ST 40          // P round-trip stride in halves: 32 + 8 pad

typedef _Float16       half8  __attribute__((ext_vector_type(8)));
typedef short          bf16x8 __attribute__((ext_vector_type(8)));
typedef float          f32x4  __attribute__((ext_vector_type(4)));

static __device__ __forceinline__ unsigned short f2bf(float f) {
    union { __hip_bfloat16 h; unsigned short u; } cv;
    cv.h = __float2bfloat16(f);
    return cv.u;
}

// ---------------------------------------------------------------------------
// Prep: item_emb fp32 -> itemH f16 [item][dim] (S B-frags) and
//       itemT bf16 [dim][item] (PV B-frags). 4 MB total, L2/L3-resident.
// ---------------------------------------------------------------------------
__global__ __launch_bounds__(256)
void prep_items(const float* __restrict__ item,
                _Float16* __restrict__ itemH,
                unsigned short* __restrict__ itemT)
{
    const int i = blockIdx.x * 256 + threadIdx.x;      // item index
    const float* src = item + (size_t)i * D_N;
    f32x4 v[16];
    #pragma unroll
    for (int j = 0; j < 16; ++j) v[j] = *(const f32x4*)(src + 4 * j);

    #pragma unroll
    for (int j = 0; j < 8; ++j) {                      // f16 row, 8x half8
        half8 h;
        #pragma unroll
        for (int k = 0; k < 4; ++k) { h[k] = (_Float16)v[2*j][k]; h[4+k] = (_Float16)v[2*j+1][k]; }
        *(half8*)&itemH[(size_t)i * D_N + 8 * j] = h;
    }
    #pragma unroll
    for (int d = 0; d < 64; ++d)                       // bf16 transpose (coalesced per d)
        itemT[(size_t)d * I_N + i] = f2bf(v[d >> 2][d & 3]);
}

// ---------------------------------------------------------------------------
// Per-iteration load bundle. Two NAMED instances, all indices compile-time
// constant after unroll -> lives entirely in VGPRs (round-3's dynamic [b]
// indexing demoted these to scratch: 1 GB of HBM writes. Never again.)
// ---------------------------------------------------------------------------
struct Buf {
    int    adjv[8];    // adj for (row 4q+r, col off + n2*16 + c), bit k = r*2+n2
    half8  sb[4];      // S-matmul B-frags (f16)   [n2*2+ks]
    bf16x8 pv[4];      // PV-matmul B-frags (bf16) [nt]
};

// ---------------------------------------------------------------------------
// Main: barrier-free flash loop. Wave owns 16 users x BN=32 items/iter.
// B-fragments straight from global (itemH/itemT, L2-hot); adj streamed from
// HBM. Everything double-buffered one iteration ahead, bundles issued in
// iteration order so vmcnt waits are fine-grained. Max-free softmax (scores
// ~N(0,64): exp(s) < 2^127 always). Only LDS: per-wave P C->A round-trip.
// ---------------------------------------------------------------------------
__global__ __launch_bounds__(256, 3)
void atten_main(const float* __restrict__ user_emb,
                const _Float16* __restrict__ itemH,
                const unsigned short* __restrict__ itemT,
                const int*   __restrict__ adj,
                float* __restrict__ wsO,
                float* __restrict__ wsL,
                int items_per_ch, int iters)
{
    __shared__ unsigned short Pl[4][16 * PL_ST];   // per-wave P round-trip, bf16

    const int ch   = blockIdx.x;
    const int ub   = blockIdx.y;
    const int t    = threadIdx.x;
    const int w    = t >> 6;
    const int lane = t & 63;
    const int c    = lane & 15;     // MFMA column lane
    const int q    = lane >> 4;     // quad 0..3

    const int urow0  = ub * 64 + w * 16;
    const int ibase0 = ch * items_per_ch;

    // ---- persistent user A-fragments (f16): A[m=c][k=ks*32+q*8+j] ----
    half8 ufrag[2];
    {
        const float* up = user_emb + (size_t)(urow0 + c) * D_N + q * 8;
        #pragma unroll
        for (int ks = 0; ks < 2; ++ks) {
            f32x4 a = *(const f32x4*)(up + ks * 32);
            f32x4 b = *(const f32x4*)(up + ks * 32 + 4);
            half8 h;
            #pragma unroll
            for (int j = 0; j < 4; ++j) { h[j] = (_Float16)a[j]; h[4 + j] = (_Float16)b[j]; }
            ufrag[ks] = h;
        }
    }

    f32x4 O[4];
    #pragma unroll
    for (int nt = 0; nt < 4; ++nt) O[nt] = (f32x4){0.f, 0.f, 0.f, 0.f};
    float l_r[4] = {0.f, 0.f, 0.f, 0.f};

    // ---- base pointers ----
    const int*            adjb = adj   + (size_t)(urow0 + 4 * q) * I_N + ibase0 + c;
    const _Float16*       sbb  = itemH + (size_t)(ibase0 + c) * D_N + q * 8;
    const unsigned short* pvb  = itemT + (size_t)c * I_N + ibase0 + q * 8;

    auto prefetch = [&](Buf& Bf, int it) {
        const size_t off = (size_t)it * BN;
        #pragma unroll
        for (int r = 0; r < 4; ++r)
            #pragma unroll
            for (int n2 = 0; n2 < 2; ++n2)
                Bf.adjv[r * 2 + n2] = adjb[(size_t)r * I_N + off + n2 * 16];
        #pragma unroll
        for (int n2 = 0; n2 < 2; ++n2)
            #pragma unroll
            for (int ks = 0; ks < 2; ++ks)
                Bf.sb[n2 * 2 + ks] = *(const half8*)&sbb[(off + n2 * 16) * D_N + ks * 32];
        #pragma unroll
        for (int nt = 0; nt < 4; ++nt)
            Bf.pv[nt] = *(const bf16x8*)&pvb[(size_t)nt * 16 * I_N + off];
    };

    auto compute = [&](const Buf& Bf) {
        // adj mask (bit r*2+n2)
        unsigned mask = 0;
        #pragma unroll
        for (int k = 0; k < 8; ++k) mask |= (Bf.adjv[k] != 0 ? 1u : 0u) << k;

        // S = U * I^T  (16 users x 32 items, f16 MFMA)
        f32x4 S[2];
        #pragma unroll
        for (int n2 = 0; n2 < 2; ++n2) {
            f32x4 acc = (f32x4){0.f, 0.f, 0.f, 0.f};
            #pragma unroll
            for (int ks = 0; ks < 2; ++ks)
                acc = __builtin_amdgcn_mfma_f32_16x16x32_f16(ufrag[ks], Bf.sb[n2 * 2 + ks],
                                                             acc, 0, 0, 0);
            S[n2] = acc;
        }

        // mask + exp (un-normalized numerator), partial l
        #pragma unroll
        for (int r = 0; r < 4; ++r)
            #pragma unroll
            for (int n2 = 0; n2 < 2; ++n2) {
                const float s = ((mask >> (r * 2 + n2)) & 1u) ? S[n2][r] : 0.0f;
                const float p = __expf(s);
                S[n2][r] = p;
                l_r[r] += p;
            }

        // P: C-layout -> LDS (bf16) -> A-layout (per-wave region, no barrier)
        #pragma unroll
        for (int r = 0; r < 4; ++r)
            #pragma unroll
            for (int n2 = 0; n2 < 2; ++n2)
                Pl[w][(4 * q + r) * PL_ST + n2 * 16 + c] = f2bf(S[n2][r]);

        bf16x8 pfrag = *(const bf16x8*)&Pl[w][c * PL_ST + q * 8];

        // O += P * V (bf16 MFMA, k = 32 items)
        #pragma unroll
        for (int nt = 0; nt < 4; ++nt)
            O[nt] = __builtin_amdgcn_mfma_f32_16x16x32_bf16(pfrag, Bf.pv[nt], O[nt], 0, 0, 0);
    };

    Buf A, B;
    prefetch(A, 0);
    prefetch(B, 1);
    // iters = 64 here: even, >= 4. Steady-state body has no branches.
    int it = 0;
    for (; it < iters - 2; it += 2) {
        compute(A);
        prefetch(A, it + 2);
        compute(B);
        prefetch(B, it + 3);
    }
    compute(A);
    compute(B);

    // ---- one-time l reduction across the 16 lanes of each quad-row ----
    #pragma unroll
    for (int r = 0; r < 4; ++r) {
        float v = l_r[r];
        #pragma unroll
        for (int offx = 1; offx < 16; offx <<= 1) v += __shfl_xor(v, offx);
        l_r[r] = v;
    }

    // ---- write chunk partials ----
    #pragma unroll
    for (int r = 0; r < 4; ++r) {
        const int u = urow0 + 4 * q + r;
        float* dst = wsO + ((size_t)ch * U_N + u) * D_N;
        #pragma unroll
        for (int nt = 0; nt < 4; ++nt)
            dst[16 * nt + c] = O[nt][r];
    }
    if (c == 0) {
        #pragma unroll
        for (int r = 0; r < 4; ++r)
            wsL[(size_t)ch * U_N + urow0 + 4 * q + r] = l_r[r];
    }
}

// ---------------------------------------------------------------------------
// Combine: sum chunk partials, normalize by total l, project by attention_weight.
// ---------------------------------------------------------------------------
__global__ __launch_bounds__(256)
void atten_combine(const float* __restrict__ wsO,
                   const float* __restrict__ wsL,
                   const float* __restrict__ attw,
                   float* __restrict__ out,
                   int nch)
{
    __shared__ float inv[64];
    __shared__ float agg[64][68];
    __shared__ float Wl[64][68];

    const int t  = threadIdx.x;
    const int u0 = blockIdx.x * 64;

    {   // stage W
        const int d = t >> 2, o0 = (t & 3) * 16;
        const float* src = attw + d * OUT_N + o0;
        #pragma unroll
        for (int j = 0; j < 4; ++j)
            *(f32x4*)&Wl[d][o0 + 4 * j] = *(const f32x4*)(src + 4 * j);
    }
    if (t < 64) {
        float L = 0.f;
        for (int cc = 0; cc < nch; ++cc) L += wsL[(size_t)cc * U_N + u0 + t];
        inv[t] = 1.0f / L;
    }
    __syncthreads();

    {   // agg[u][d] = (sum_c O_c[u][d]) / L[u]
        const int ul = t >> 2, d0 = (t & 3) * 16;
        const int u = u0 + ul;
        f32x4 a4[4];
        #pragma unroll
        for (int j = 0; j < 4; ++j) a4[j] = (f32x4){0.f, 0.f, 0.f, 0.f};
        for (int cc = 0; cc < nch; ++cc) {
            const float* src = wsO + ((size_t)cc * U_N + u) * D_N + d0;
            #pragma unroll
            for (int j = 0; j < 4; ++j) a4[j] += *(const f32x4*)(src + 4 * j);
        }
        const float s = inv[ul];
        #pragma unroll
        for (int j = 0; j < 4; ++j)
            *(f32x4*)&agg[ul][d0 + 4 * j] = a4[j] * s;
    }
    __syncthreads();

    {   // out[u][o] = sum_d agg[u][d] * W[d][o]
        const int ul = t >> 2, o0 = (t & 3) * 16;
        f32x4 acc[4];
        #pragma unroll
        for (int j = 0; j < 4; ++j) acc[j] = (f32x4){0.f, 0.f, 0.f, 0.f};
        for (int d = 0; d < 64; ++d) {
            const float av = agg[ul][d];
            #pragma unroll
            for (int j = 0; j < 4; ++j) {
                f32x4 wv = *(const f32x4*)&Wl[d][o0 + 4 * j];
                acc[j] += wv * av;
            }
        }
        float* dst = out + (size_t)(u0 + ul) * OUT_N + o0;
        #pragma unroll
        for (int j = 0; j < 4; ++j)
            *(f32x4*)(dst + 4 * j) = acc[j];
    }
}

// ---------------------------------------------------------------------------
extern "C" void kernel_launch(void* const* d_in, const int* in_sizes, int n_in,
                              void* d_out, int out_size, void* d_ws, size_t ws_size,
                              hipStream_t stream)
{
    const float* user_emb = (const float*)d_in[0];
    const float* item_emb = (const float*)d_in[1];
    const float* attw     = (const float*)d_in[2];
    const int*   adj      = (const int*)d_in[3];
    float* out = (float*)d_out;

    const int nch = 8;

    // ws layout: wsO | wsL | itemH | itemT
    float*          wsO   = (float*)d_ws;
    float*          wsL   = wsO + (size_t)nch * U_N * D_N;
    _Float16*       itemH = (_Float16*)(wsL + (size_t)nch * U_N);
    unsigned short* itemT = (unsigned short*)(itemH + (size_t)I_N * D_N);

    const int items_per_ch = I_N / nch;          // 2048
    const int iters = items_per_ch / BN;         // 64 (even, >= 4)

    prep_items<<<dim3(I_N / 256), 256, 0, stream>>>(item_emb, itemH, itemT);
    atten_main<<<dim3(nch, U_N / 64), 256, 0, stream>>>(user_emb, itemH, itemT, adj,
                                                        wsO, wsL, items_per_ch, iters);
    atten_combine<<<dim3(U_N / 64), 256, 0, stream>>>(wsO, wsL, attw, out, nch);
}

// Round 5
// 839.008 us; speedup vs baseline: 1.5055x; 1.3527x over previous
//
#include <hip/hip_runtime.h>
#include <hip/hip_bf16.h>
#include <math.h>

#define U_N   8192
#define I_N   16384
#define D_N   64
#define OUT_N 64
#define BN    32          // items per wave-iteration
#define PL_ST 40          // P round-trip stride in halves: 32 + 8 pad

typedef _Float16       half8  __attribute__((ext_vector_type(8)));
typedef short          bf16x8 __attribute__((ext_vector_type(8)));
typedef float          f32x4  __attribute__((ext_vector_type(4)));

static __device__ __forceinline__ unsigned short f2bf(float f) {
    union { __hip_bfloat16 h; unsigned short u; } cv;
    cv.h = __float2bfloat16(f);
    return cv.u;
}

static __device__ __forceinline__ float rsum16(float v) {
    #pragma unroll
    for (int o = 1; o < 16; o <<= 1) v += __shfl_xor(v, o);
    return v;
}

// ---------------------------------------------------------------------------
// Prep: item_emb fp32 -> itemH f16 [item][dim] (S B-frags) and
//       itemT bf16 [dim][item] (PV B-frags). 4 MB total, L2/L3-resident.
// ---------------------------------------------------------------------------
__global__ __launch_bounds__(256)
void prep_items(const float* __restrict__ item,
                _Float16* __restrict__ itemH,
                unsigned short* __restrict__ itemT)
{
    const int i = blockIdx.x * 256 + threadIdx.x;      // item index
    const float* src = item + (size_t)i * D_N;
    f32x4 v[16];
    #pragma unroll
    for (int j = 0; j < 16; ++j) v[j] = *(const f32x4*)(src + 4 * j);

    #pragma unroll
    for (int j = 0; j < 8; ++j) {                      // f16 row, 8x half8
        half8 h;
        #pragma unroll
        for (int k = 0; k < 4; ++k) { h[k] = (_Float16)v[2*j][k]; h[4+k] = (_Float16)v[2*j+1][k]; }
        *(half8*)&itemH[(size_t)i * D_N + 8 * j] = h;
    }
    #pragma unroll
    for (int d = 0; d < 64; ++d)                       // bf16 transpose (coalesced per d)
        itemT[(size_t)d * I_N + i] = f2bf(v[d >> 2][d & 3]);
}

// ---------------------------------------------------------------------------
// Pipeline state as INDIVIDUALLY NAMED registers via token pasting. Round 3
// (dynamic index) and round 4 (struct+lambda) both demoted the double-buffer
// to scratch => ~1 GB/dispatch of HBM scratch writes. No arrays, no structs,
// no lambdas: nothing for SROA to miss.
// ---------------------------------------------------------------------------
#define DECL_BUF(BUF) \
    int   adj##BUF##0, adj##BUF##1, adj##BUF##2, adj##BUF##3, \
          adj##BUF##4, adj##BUF##5, adj##BUF##6, adj##BUF##7; \
    half8 sb##BUF##0, sb##BUF##1, sb##BUF##2, sb##BUF##3;

// adj bit k = r*2+n2 at (row 4q+r, col it*BN + n2*16 + c)
#define PREFETCH(BUF, it_) do { \
    const size_t off_ = (size_t)(it_) * BN; \
    adj##BUF##0 = adjb[0 * (size_t)I_N + off_ +  0]; \
    adj##BUF##1 = adjb[0 * (size_t)I_N + off_ + 16]; \
    adj##BUF##2 = adjb[1 * (size_t)I_N + off_ +  0]; \
    adj##BUF##3 = adjb[1 * (size_t)I_N + off_ + 16]; \
    adj##BUF##4 = adjb[2 * (size_t)I_N + off_ +  0]; \
    adj##BUF##5 = adjb[2 * (size_t)I_N + off_ + 16]; \
    adj##BUF##6 = adjb[3 * (size_t)I_N + off_ +  0]; \
    adj##BUF##7 = adjb[3 * (size_t)I_N + off_ + 16]; \
    sb##BUF##0 = *(const half8*)&sbb[(off_ +  0) * D_N +  0]; \
    sb##BUF##1 = *(const half8*)&sbb[(off_ +  0) * D_N + 32]; \
    sb##BUF##2 = *(const half8*)&sbb[(off_ + 16) * D_N +  0]; \
    sb##BUF##3 = *(const half8*)&sbb[(off_ + 16) * D_N + 32]; \
} while (0)

// PV frags (L2-hot) issued at top, consumed at bottom: hidden under S+exp.
#define COMPUTE(BUF, it_) do { \
    const size_t off_ = (size_t)(it_) * BN; \
    bf16x8 pv0_ = *(const bf16x8*)&pvb[ 0 * (size_t)I_N + off_]; \
    bf16x8 pv1_ = *(const bf16x8*)&pvb[16 * (size_t)I_N + off_]; \
    bf16x8 pv2_ = *(const bf16x8*)&pvb[32 * (size_t)I_N + off_]; \
    bf16x8 pv3_ = *(const bf16x8*)&pvb[48 * (size_t)I_N + off_]; \
    f32x4 S0_ = (f32x4){0.f,0.f,0.f,0.f}; \
    f32x4 S1_ = (f32x4){0.f,0.f,0.f,0.f}; \
    S0_ = __builtin_amdgcn_mfma_f32_16x16x32_f16(ufrag0, sb##BUF##0, S0_, 0, 0, 0); \
    S0_ = __builtin_amdgcn_mfma_f32_16x16x32_f16(ufrag1, sb##BUF##1, S0_, 0, 0, 0); \
    S1_ = __builtin_amdgcn_mfma_f32_16x16x32_f16(ufrag0, sb##BUF##2, S1_, 0, 0, 0); \
    S1_ = __builtin_amdgcn_mfma_f32_16x16x32_f16(ufrag1, sb##BUF##3, S1_, 0, 0, 0); \
    float e_; \
    e_ = __expf((adj##BUF##0 != 0) ? S0_[0] : 0.0f); S0_[0] = e_; l0 += e_; \
    e_ = __expf((adj##BUF##1 != 0) ? S1_[0] : 0.0f); S1_[0] = e_; l0 += e_; \
    e_ = __expf((adj##BUF##2 != 0) ? S0_[1] : 0.0f); S0_[1] = e_; l1 += e_; \
    e_ = __expf((adj##BUF##3 != 0) ? S1_[1] : 0.0f); S1_[1] = e_; l1 += e_; \
    e_ = __expf((adj##BUF##4 != 0) ? S0_[2] : 0.0f); S0_[2] = e_; l2 += e_; \
    e_ = __expf((adj##BUF##5 != 0) ? S1_[2] : 0.0f); S1_[2] = e_; l2 += e_; \
    e_ = __expf((adj##BUF##6 != 0) ? S0_[3] : 0.0f); S0_[3] = e_; l3 += e_; \
    e_ = __expf((adj##BUF##7 != 0) ? S1_[3] : 0.0f); S1_[3] = e_; l3 += e_; \
    plw[(4*q+0)*PL_ST +  0 + c] = f2bf(S0_[0]); \
    plw[(4*q+0)*PL_ST + 16 + c] = f2bf(S1_[0]); \
    plw[(4*q+1)*PL_ST +  0 + c] = f2bf(S0_[1]); \
    plw[(4*q+1)*PL_ST + 16 + c] = f2bf(S1_[1]); \
    plw[(4*q+2)*PL_ST +  0 + c] = f2bf(S0_[2]); \
    plw[(4*q+2)*PL_ST + 16 + c] = f2bf(S1_[2]); \
    plw[(4*q+3)*PL_ST +  0 + c] = f2bf(S0_[3]); \
    plw[(4*q+3)*PL_ST + 16 + c] = f2bf(S1_[3]); \
    bf16x8 pf_ = *(const bf16x8*)&plw[c * PL_ST + q * 8]; \
    O0 = __builtin_amdgcn_mfma_f32_16x16x32_bf16(pf_, pv0_, O0, 0, 0, 0); \
    O1 = __builtin_amdgcn_mfma_f32_16x16x32_bf16(pf_, pv1_, O1, 0, 0, 0); \
    O2 = __builtin_amdgcn_mfma_f32_16x16x32_bf16(pf_, pv2_, O2, 0, 0, 0); \
    O3 = __builtin_amdgcn_mfma_f32_16x16x32_bf16(pf_, pv3_, O3, 0, 0, 0); \
} while (0)

// ---------------------------------------------------------------------------
// Main: barrier-free flash loop. Wave owns 16 users x BN=32 items/iter.
// B-frags straight from global (itemH/itemT, L2-hot); adj streamed from HBM,
// double-buffered 2 iters ahead in named registers. Max-free softmax (scores
// ~N(0,64): exp(s) finite in fp32/bf16). Only LDS: per-wave P C->A round-trip.
// ---------------------------------------------------------------------------
__global__ __launch_bounds__(256, 3)
void atten_main(const float* __restrict__ user_emb,
                const _Float16* __restrict__ itemH,
                const unsigned short* __restrict__ itemT,
                const int*   __restrict__ adj,
                float* __restrict__ wsO,
                float* __restrict__ wsL,
                int items_per_ch, int iters)
{
    __shared__ unsigned short Pl[4][16 * PL_ST];   // per-wave P round-trip, bf16

    const int ch   = blockIdx.x;
    const int ub   = blockIdx.y;
    const int t    = threadIdx.x;
    const int w    = t >> 6;
    const int lane = t & 63;
    const int c    = lane & 15;     // MFMA column lane
    const int q    = lane >> 4;     // quad 0..3

    const int urow0  = ub * 64 + w * 16;
    const int ibase0 = ch * items_per_ch;

    unsigned short* plw = &Pl[w][0];

    // ---- persistent user A-fragments (f16): A[m=c][k=ks*32+q*8+j] ----
    half8 ufrag0, ufrag1;
    {
        const float* up = user_emb + (size_t)(urow0 + c) * D_N + q * 8;
        f32x4 a0 = *(const f32x4*)(up);
        f32x4 b0 = *(const f32x4*)(up + 4);
        f32x4 a1 = *(const f32x4*)(up + 32);
        f32x4 b1 = *(const f32x4*)(up + 36);
        #pragma unroll
        for (int j = 0; j < 4; ++j) {
            ufrag0[j] = (_Float16)a0[j]; ufrag0[4 + j] = (_Float16)b0[j];
            ufrag1[j] = (_Float16)a1[j]; ufrag1[4 + j] = (_Float16)b1[j];
        }
    }

    f32x4 O0 = (f32x4){0.f,0.f,0.f,0.f};
    f32x4 O1 = O0, O2 = O0, O3 = O0;
    float l0 = 0.f, l1 = 0.f, l2 = 0.f, l3 = 0.f;

    // ---- base pointers ----
    const int*            adjb = adj   + (size_t)(urow0 + 4 * q) * I_N + ibase0 + c;
    const _Float16*       sbb  = itemH + (size_t)(ibase0 + c) * D_N + q * 8;
    const unsigned short* pvb  = itemT + (size_t)c * I_N + ibase0 + q * 8;

    DECL_BUF(A)
    DECL_BUF(B)

    PREFETCH(A, 0);
    PREFETCH(B, 1);

    // iters = 64: even, >= 4. Steady-state body branch-free.
    int it = 0;
    for (; it < iters - 2; it += 2) {
        COMPUTE(A, it);
        PREFETCH(A, it + 2);
        COMPUTE(B, it + 1);
        PREFETCH(B, it + 3);
    }
    COMPUTE(A, iters - 2);
    COMPUTE(B, iters - 1);

    // ---- one-time l reduction across the 16 lanes of each quad-row ----
    l0 = rsum16(l0); l1 = rsum16(l1); l2 = rsum16(l2); l3 = rsum16(l3);

    // ---- write chunk partials ----
    {
        float* d0 = wsO + ((size_t)ch * U_N + urow0 + 4 * q + 0) * D_N;
        float* d1 = wsO + ((size_t)ch * U_N + urow0 + 4 * q + 1) * D_N;
        float* d2 = wsO + ((size_t)ch * U_N + urow0 + 4 * q + 2) * D_N;
        float* d3 = wsO + ((size_t)ch * U_N + urow0 + 4 * q + 3) * D_N;
        d0[c] = O0[0]; d0[16 + c] = O1[0]; d0[32 + c] = O2[0]; d0[48 + c] = O3[0];
        d1[c] = O0[1]; d1[16 + c] = O1[1]; d1[32 + c] = O2[1]; d1[48 + c] = O3[1];
        d2[c] = O0[2]; d2[16 + c] = O1[2]; d2[32 + c] = O2[2]; d2[48 + c] = O3[2];
        d3[c] = O0[3]; d3[16 + c] = O1[3]; d3[32 + c] = O2[3]; d3[48 + c] = O3[3];
    }
    if (c == 0) {
        float* lw = wsL + (size_t)ch * U_N + urow0 + 4 * q;
        lw[0] = l0; lw[1] = l1; lw[2] = l2; lw[3] = l3;
    }
}

// ---------------------------------------------------------------------------
// Combine: sum chunk partials, normalize by total l, project by attention_weight.
// ---------------------------------------------------------------------------
__global__ __launch_bounds__(256)
void atten_combine(const float* __restrict__ wsO,
                   const float* __restrict__ wsL,
                   const float* __restrict__ attw,
                   float* __restrict__ out,
                   int nch)
{
    __shared__ float inv[64];
    __shared__ float agg[64][68];
    __shared__ float Wl[64][68];

    const int t  = threadIdx.x;
    const int u0 = blockIdx.x * 64;

    {   // stage W
        const int d = t >> 2, o0 = (t & 3) * 16;
        const float* src = attw + d * OUT_N + o0;
        #pragma unroll
        for (int j = 0; j < 4; ++j)
            *(f32x4*)&Wl[d][o0 + 4 * j] = *(const f32x4*)(src + 4 * j);
    }
    if (t < 64) {
        float L = 0.f;
        for (int cc = 0; cc < nch; ++cc) L += wsL[(size_t)cc * U_N + u0 + t];
        inv[t] = 1.0f / L;
    }
    __syncthreads();

    {   // agg[u][d] = (sum_c O_c[u][d]) / L[u]
        const int ul = t >> 2, d0 = (t & 3) * 16;
        const int u = u0 + ul;
        f32x4 a4[4];
        #pragma unroll
        for (int j = 0; j < 4; ++j) a4[j] = (f32x4){0.f, 0.f, 0.f, 0.f};
        for (int cc = 0; cc < nch; ++cc) {
            const float* src = wsO + ((size_t)cc * U_N + u) * D_N + d0;
            #pragma unroll
            for (int j = 0; j < 4; ++j) a4[j] += *(const f32x4*)(src + 4 * j);
        }
        const float s = inv[ul];
        #pragma unroll
        for (int j = 0; j < 4; ++j)
            *(f32x4*)&agg[ul][d0 + 4 * j] = a4[j] * s;
    }
    __syncthreads();

    {   // out[u][o] = sum_d agg[u][d] * W[d][o]
        const int ul = t >> 2, o0 = (t & 3) * 16;
        f32x4 acc[4];
        #pragma unroll
        for (int j = 0; j < 4; ++j) acc[j] = (f32x4){0.f, 0.f, 0.f, 0.f};
        for (int d = 0; d < 64; ++d) {
            const float av = agg[ul][d];
            #pragma unroll
            for (int j = 0; j < 4; ++j) {
                f32x4 wv = *(const f32x4*)&Wl[d][o0 + 4 * j];
                acc[j] += wv * av;
            }
        }
        float* dst = out + (size_t)(u0 + ul) * OUT_N + o0;
        #pragma unroll
        for (int j = 0; j < 4; ++j)
            *(f32x4*)(dst + 4 * j) = acc[j];
    }
}

// ---------------------------------------------------------------------------
extern "C" void kernel_launch(void* const* d_in, const int* in_sizes, int n_in,
                              void* d_out, int out_size, void* d_ws, size_t ws_size,
                              hipStream_t stream)
{
    const float* user_emb = (const float*)d_in[0];
    const float* item_emb = (const float*)d_in[1];
    const float* attw     = (const float*)d_in[2];
    const int*   adj      = (const int*)d_in[3];
    float* out = (float*)d_out;

    const int nch = 8;

    // ws layout: wsO | wsL | itemH | itemT
    float*          wsO   = (float*)d_ws;
    float*          wsL   = wsO + (size_t)nch * U_N * D_N;
    _Float16*       itemH = (_Float16*)(wsL + (size_t)nch * U_N);
    unsigned short* itemT = (unsigned short*)(itemH + (size_t)I_N * D_N);

    const int items_per_ch = I_N / nch;          // 2048
    const int iters = items_per_ch / BN;         // 64 (even, >= 4)

    prep_items<<<dim3(I_N / 256), 256, 0, stream>>>(item_emb, itemH, itemT);
    atten_main<<<dim3(nch, U_N / 64), 256, 0, stream>>>(user_emb, itemH, itemT, adj,
                                                        wsO, wsL, items_per_ch, iters);
    atten_combine<<<dim3(U_N / 64), 256, 0, stream>>>(wsO, wsL, attw, out, nch);
}

// Round 6
// 723.766 us; speedup vs baseline: 1.7452x; 1.1592x over previous
//
#include <hip/hip_runtime.h>
#include <hip/hip_bf16.h>
#include <math.h>

#define U_N   8192
#define I_N   16384
#define D_N   64
#define OUT_N 64
#define BN    32           // items per iteration tile
#define NCH   8            // item chunks (split-K)
#define ITERS 64           // (I_N/NCH)/BN
#define VN_ST 72           // Vn stride (halves): 144B rows, b128 reads 2-way-free
#define VT_ST 36           // Vt stride (halves): 72B rows, b64 reads 2-way-free
#define PL_ST 40           // P round-trip stride (halves), 80B rows (b128-aligned)

typedef _Float16 half8  __attribute__((ext_vector_type(8)));
typedef short    bf16x8 __attribute__((ext_vector_type(8)));
typedef short    bf16x4 __attribute__((ext_vector_type(4)));
typedef float    f32x4  __attribute__((ext_vector_type(4)));

static __device__ __forceinline__ unsigned short f2bf(float f) {
    union { __hip_bfloat16 h; unsigned short u; } cv;
    cv.h = __float2bfloat16(f);
    return cv.u;
}
static __device__ __forceinline__ float rsum16(float v) {
    #pragma unroll
    for (int o = 1; o < 16; o <<= 1) v += __shfl_xor(v, o);
    return v;
}
// Barrier WITHOUT vmcnt drain: LDS-only wait. Global prefetches stay in
// flight across it (compiler's __syncthreads pins s_waitcnt vmcnt(0) - the
// m97 stall; this is the AITER-style replacement).
static __device__ __forceinline__ void bar() {
    asm volatile("s_waitcnt lgkmcnt(0)\n\ts_barrier" ::: "memory");
}

// ---------------------------------------------------------------------------
// Prep: item_emb fp32 -> itemH f16 [item][dim] and itemTt bf16 tiled
// transpose [item>>5][dim][item&31] (so staging is contiguous 16B copies).
// ---------------------------------------------------------------------------
__global__ __launch_bounds__(256)
void prep_items(const float* __restrict__ item,
                _Float16* __restrict__ itemH,
                unsigned short* __restrict__ itemTt)
{
    const int i = blockIdx.x * 256 + threadIdx.x;      // item index
    const float* src = item + (size_t)i * D_N;
    f32x4 v[16];
    #pragma unroll
    for (int j = 0; j < 16; ++j) v[j] = *(const f32x4*)(src + 4 * j);

    #pragma unroll
    for (int j = 0; j < 8; ++j) {                      // f16 row
        half8 h;
        #pragma unroll
        for (int k = 0; k < 4; ++k) { h[k] = (_Float16)v[2*j][k]; h[4+k] = (_Float16)v[2*j+1][k]; }
        *(half8*)&itemH[(size_t)i * D_N + 8 * j] = h;
    }
    const size_t tb = (size_t)(i >> 5) * (D_N * 32) + (i & 31);
    #pragma unroll
    for (int d = 0; d < 64; ++d)                       // tiled bf16 transpose
        itemTt[tb + (size_t)d * 32] = f2bf(v[d >> 2][d & 3]);
}

// ---------------------------------------------------------------------------
// Named-register pipeline state (arrays/structs/lambdas get demoted to
// scratch -> 1 GB HBM writes, r3/r4 lesson).
// ---------------------------------------------------------------------------
#define DECL_SET(S) \
    int adj##S##0, adj##S##1, adj##S##2, adj##S##3, \
        adj##S##4, adj##S##5, adj##S##6, adj##S##7;  \
    half8 vn##S; bf16x8 vt##S;

#define LOAD_ADJ(S, tidx) do { \
    const size_t o_ = (size_t)(tidx) * BN; \
    adj##S##0 = adjb[0 * (size_t)I_N + o_ +  0]; \
    adj##S##1 = adjb[0 * (size_t)I_N + o_ + 16]; \
    adj##S##2 = adjb[1 * (size_t)I_N + o_ +  0]; \
    adj##S##3 = adjb[1 * (size_t)I_N + o_ + 16]; \
    adj##S##4 = adjb[2 * (size_t)I_N + o_ +  0]; \
    adj##S##5 = adjb[2 * (size_t)I_N + o_ + 16]; \
    adj##S##6 = adjb[3 * (size_t)I_N + o_ +  0]; \
    adj##S##7 = adjb[3 * (size_t)I_N + o_ + 16]; \
} while (0)

#define LOAD_TILE(S, tidx) do { \
    const size_t o_ = (size_t)(tidx) * BN; \
    vn##S = *(const half8*)&itemH[(ibase0 + o_ + (t >> 3)) * D_N + (t & 7) * 8]; \
    vt##S = *(const bf16x8*)&itemTt[((ibase0 + o_) >> 5) * (D_N * 32) \
                                    + (size_t)(t >> 2) * 32 + (t & 3) * 8]; \
} while (0)

#define COMMIT(S, bufw) do { \
    *(half8*)&Vn[bufw][(t >> 3) * VN_ST + (t & 7) * 8] = vn##S; \
    *(bf16x4*)&Vt[bufw][(t >> 2) * VT_ST + (t & 3) * 8]     = \
        __builtin_shufflevector(vt##S, vt##S, 0, 1, 2, 3); \
    *(bf16x4*)&Vt[bufw][(t >> 2) * VT_ST + (t & 3) * 8 + 4] = \
        __builtin_shufflevector(vt##S, vt##S, 4, 5, 6, 7); \
} while (0)

#define MASK_OF(S) \
    (((adj##S##0 != 0) ? 1u : 0u)       | ((adj##S##1 != 0) ? 2u : 0u) | \
     ((adj##S##2 != 0) ? 4u : 0u)       | ((adj##S##3 != 0) ? 8u : 0u) | \
     ((adj##S##4 != 0) ? 16u : 0u)      | ((adj##S##5 != 0) ? 32u : 0u) | \
     ((adj##S##6 != 0) ? 64u : 0u)      | ((adj##S##7 != 0) ? 128u : 0u))

#define COMPUTE_REST(msk, bufr) do { \
    half8 b00 = *(const half8*)&Vn[bufr][(c)      * VN_ST      + q * 8]; \
    half8 b01 = *(const half8*)&Vn[bufr][(c)      * VN_ST + 32 + q * 8]; \
    half8 b10 = *(const half8*)&Vn[bufr][(16 + c) * VN_ST      + q * 8]; \
    half8 b11 = *(const half8*)&Vn[bufr][(16 + c) * VN_ST + 32 + q * 8]; \
    f32x4 S0 = (f32x4){0.f,0.f,0.f,0.f}; \
    f32x4 S1 = (f32x4){0.f,0.f,0.f,0.f}; \
    S0 = __builtin_amdgcn_mfma_f32_16x16x32_f16(ufrag0, b00, S0, 0, 0, 0); \
    S0 = __builtin_amdgcn_mfma_f32_16x16x32_f16(ufrag1, b01, S0, 0, 0, 0); \
    S1 = __builtin_amdgcn_mfma_f32_16x16x32_f16(ufrag0, b10, S1, 0, 0, 0); \
    S1 = __builtin_amdgcn_mfma_f32_16x16x32_f16(ufrag1, b11, S1, 0, 0, 0); \
    float e_; \
    e_ = __expf(((msk) &   1u) ? S0[0] : 0.0f); S0[0] = e_; l0 += e_; \
    e_ = __expf(((msk) &   2u) ? S1[0] : 0.0f); S1[0] = e_; l0 += e_; \
    e_ = __expf(((msk) &   4u) ? S0[1] : 0.0f); S0[1] = e_; l1 += e_; \
    e_ = __expf(((msk) &   8u) ? S1[1] : 0.0f); S1[1] = e_; l1 += e_; \
    e_ = __expf(((msk) &  16u) ? S0[2] : 0.0f); S0[2] = e_; l2 += e_; \
    e_ = __expf(((msk) &  32u) ? S1[2] : 0.0f); S1[2] = e_; l2 += e_; \
    e_ = __expf(((msk) &  64u) ? S0[3] : 0.0f); S0[3] = e_; l3 += e_; \
    e_ = __expf(((msk) & 128u) ? S1[3] : 0.0f); S1[3] = e_; l3 += e_; \
    plw[(4*q+0)*PL_ST +  0 + c] = f2bf(S0[0]); \
    plw[(4*q+0)*PL_ST + 16 + c] = f2bf(S1[0]); \
    plw[(4*q+1)*PL_ST +  0 + c] = f2bf(S0[1]); \
    plw[(4*q+1)*PL_ST + 16 + c] = f2bf(S1[1]); \
    plw[(4*q+2)*PL_ST +  0 + c] = f2bf(S0[2]); \
    plw[(4*q+2)*PL_ST + 16 + c] = f2bf(S1[2]); \
    plw[(4*q+3)*PL_ST +  0 + c] = f2bf(S0[3]); \
    plw[(4*q+3)*PL_ST + 16 + c] = f2bf(S1[3]); \
    bf16x8 pf = *(const bf16x8*)&plw[c * PL_ST + q * 8]; \
    bf16x4 va0 = *(const bf16x4*)&Vt[bufr][(c)      * VT_ST + q * 8]; \
    bf16x4 vb0 = *(const bf16x4*)&Vt[bufr][(c)      * VT_ST + q * 8 + 4]; \
    bf16x4 va1 = *(const bf16x4*)&Vt[bufr][(16 + c) * VT_ST + q * 8]; \
    bf16x4 vb1 = *(const bf16x4*)&Vt[bufr][(16 + c) * VT_ST + q * 8 + 4]; \
    bf16x4 va2 = *(const bf16x4*)&Vt[bufr][(32 + c) * VT_ST + q * 8]; \
    bf16x4 vb2 = *(const bf16x4*)&Vt[bufr][(32 + c) * VT_ST + q * 8 + 4]; \
    bf16x4 va3 = *(const bf16x4*)&Vt[bufr][(48 + c) * VT_ST + q * 8]; \
    bf16x4 vb3 = *(const bf16x4*)&Vt[bufr][(48 + c) * VT_ST + q * 8 + 4]; \
    bf16x8 v0 = __builtin_shufflevector(va0, vb0, 0,1,2,3,4,5,6,7); \
    bf16x8 v1 = __builtin_shufflevector(va1, vb1, 0,1,2,3,4,5,6,7); \
    bf16x8 v2 = __builtin_shufflevector(va2, vb2, 0,1,2,3,4,5,6,7); \
    bf16x8 v3 = __builtin_shufflevector(va3, vb3, 0,1,2,3,4,5,6,7); \
    O0 = __builtin_amdgcn_mfma_f32_16x16x32_bf16(pf, v0, O0, 0, 0, 0); \
    O1 = __builtin_amdgcn_mfma_f32_16x16x32_bf16(pf, v1, O1, 0, 0, 0); \
    O2 = __builtin_amdgcn_mfma_f32_16x16x32_bf16(pf, v2, O2, 0, 0, 0); \
    O3 = __builtin_amdgcn_mfma_f32_16x16x32_bf16(pf, v3, O3, 0, 0, 0); \
} while (0)

// ---------------------------------------------------------------------------
// Main: cooperative ping-pong LDS staging, one LDS-only barrier per iter,
// global prefetches in flight across barriers. Tile j: loaded iter j-2,
// committed iter j-1, consumed iter j. adj consumed from named regs.
// ---------------------------------------------------------------------------
__global__ __launch_bounds__(256, 3)
void atten_main(const float* __restrict__ user_emb,
                const _Float16* __restrict__ itemH,
                const unsigned short* __restrict__ itemTt,
                const int*   __restrict__ adj,
                float* __restrict__ wsO,
                float* __restrict__ wsL)
{
    __shared__ _Float16 Vn[2][BN * VN_ST];         // [item][dim] f16   (S B-frags)
    __shared__ short    Vt[2][D_N * VT_ST];        // [dim][item] bf16  (PV B-frags)
    __shared__ unsigned short Pl[4][16 * PL_ST];   // per-wave P round-trip

    const int ch   = blockIdx.x;
    const int ub   = blockIdx.y;
    const int t    = threadIdx.x;
    const int w    = t >> 6;
    const int lane = t & 63;
    const int c    = lane & 15;
    const int q    = lane >> 4;

    const int    urow0  = ub * 64 + w * 16;
    const size_t ibase0 = (size_t)ch * (I_N / NCH);

    unsigned short* plw = &Pl[w][0];

    // persistent user A-fragments (f16): A[m=c][k=ks*32+q*8+j]
    half8 ufrag0, ufrag1;
    {
        const float* up = user_emb + (size_t)(urow0 + c) * D_N + q * 8;
        f32x4 a0 = *(const f32x4*)(up);
        f32x4 b0 = *(const f32x4*)(up + 4);
        f32x4 a1 = *(const f32x4*)(up + 32);
        f32x4 b1 = *(const f32x4*)(up + 36);
        #pragma unroll
        for (int j = 0; j < 4; ++j) {
            ufrag0[j] = (_Float16)a0[j]; ufrag0[4 + j] = (_Float16)b0[j];
            ufrag1[j] = (_Float16)a1[j]; ufrag1[4 + j] = (_Float16)b1[j];
        }
    }

    f32x4 O0 = (f32x4){0.f,0.f,0.f,0.f};
    f32x4 O1 = O0, O2 = O0, O3 = O0;
    float l0 = 0.f, l1 = 0.f, l2 = 0.f, l3 = 0.f;

    const int* adjb = adj + (size_t)(urow0 + 4 * q) * I_N + ibase0 + c;

    DECL_SET(A)
    DECL_SET(B)

    // prologue: tiles 0,1 -> regs; commit 0 -> LDS[0]; reload A-tile with 2
    LOAD_TILE(A, 0); LOAD_ADJ(A, 0);
    LOAD_TILE(B, 1); LOAD_ADJ(B, 1);
    COMMIT(A, 0);
    LOAD_TILE(A, 2);
    bar();

    for (int k = 0; k < ITERS; k += 2) {
        {   // iter k: consume buf0 + adjA; commit B->buf1; load adjA<-k+2, tileB<-k+3
            const unsigned msk = MASK_OF(A);
            COMMIT(B, 1);
            const int ia = (k + 2 < ITERS) ? k + 2 : ITERS - 1;
            const int iv = (k + 3 < ITERS) ? k + 3 : ITERS - 1;
            LOAD_ADJ(A, ia);
            LOAD_TILE(B, iv);
            COMPUTE_REST(msk, 0);
            bar();
        }
        {   // iter k+1: consume buf1 + adjB; commit A->buf0; load adjB<-k+3, tileA<-k+4
            const unsigned msk = MASK_OF(B);
            COMMIT(A, 0);
            const int ia = (k + 3 < ITERS) ? k + 3 : ITERS - 1;
            const int iv = (k + 4 < ITERS) ? k + 4 : ITERS - 1;
            LOAD_ADJ(B, ia);
            LOAD_TILE(A, iv);
            COMPUTE_REST(msk, 1);
            bar();
        }
    }

    // one-time l reduction across the 16 lanes of each quad-row
    l0 = rsum16(l0); l1 = rsum16(l1); l2 = rsum16(l2); l3 = rsum16(l3);

    // write chunk partials
    {
        float* d0 = wsO + ((size_t)ch * U_N + urow0 + 4 * q + 0) * D_N;
        float* d1 = wsO + ((size_t)ch * U_N + urow0 + 4 * q + 1) * D_N;
        float* d2 = wsO + ((size_t)ch * U_N + urow0 + 4 * q + 2) * D_N;
        float* d3 = wsO + ((size_t)ch * U_N + urow0 + 4 * q + 3) * D_N;
        d0[c] = O0[0]; d0[16 + c] = O1[0]; d0[32 + c] = O2[0]; d0[48 + c] = O3[0];
        d1[c] = O0[1]; d1[16 + c] = O1[1]; d1[32 + c] = O2[1]; d1[48 + c] = O3[1];
        d2[c] = O0[2]; d2[16 + c] = O1[2]; d2[32 + c] = O2[2]; d2[48 + c] = O3[2];
        d3[c] = O0[3]; d3[16 + c] = O1[3]; d3[32 + c] = O2[3]; d3[48 + c] = O3[3];
    }
    if (c == 0) {
        float* lw = wsL + (size_t)ch * U_N + urow0 + 4 * q;
        lw[0] = l0; lw[1] = l1; lw[2] = l2; lw[3] = l3;
    }
}

// ---------------------------------------------------------------------------
// Combine: sum chunk partials, normalize, project by attention_weight.
// ---------------------------------------------------------------------------
__global__ __launch_bounds__(256)
void atten_combine(const float* __restrict__ wsO,
                   const float* __restrict__ wsL,
                   const float* __restrict__ attw,
                   float* __restrict__ out,
                   int nch)
{
    __shared__ float inv[64];
    __shared__ float agg[64][68];
    __shared__ float Wl[64][68];

    const int t  = threadIdx.x;
    const int u0 = blockIdx.x * 64;

    {
        const int d = t >> 2, o0 = (t & 3) * 16;
        const float* src = attw + d * OUT_N + o0;
        #pragma unroll
        for (int j = 0; j < 4; ++j)
            *(f32x4*)&Wl[d][o0 + 4 * j] = *(const f32x4*)(src + 4 * j);
    }
    if (t < 64) {
        float L = 0.f;
        for (int cc = 0; cc < nch; ++cc) L += wsL[(size_t)cc * U_N + u0 + t];
        inv[t] = 1.0f / L;
    }
    __syncthreads();

    {
        const int ul = t >> 2, d0 = (t & 3) * 16;
        const int u = u0 + ul;
        f32x4 a4[4];
        #pragma unroll
        for (int j = 0; j < 4; ++j) a4[j] = (f32x4){0.f, 0.f, 0.f, 0.f};
        for (int cc = 0; cc < nch; ++cc) {
            const float* src = wsO + ((size_t)cc * U_N + u) * D_N + d0;
            #pragma unroll
            for (int j = 0; j < 4; ++j) a4[j] += *(const f32x4*)(src + 4 * j);
        }
        const float s = inv[ul];
        #pragma unroll
        for (int j = 0; j < 4; ++j)
            *(f32x4*)&agg[ul][d0 + 4 * j] = a4[j] * s;
    }
    __syncthreads();

    {
        const int ul = t >> 2, o0 = (t & 3) * 16;
        f32x4 acc[4];
        #pragma unroll
        for (int j = 0; j < 4; ++j) acc[j] = (f32x4){0.f, 0.f, 0.f, 0.f};
        for (int d = 0; d < 64; ++d) {
            const float av = agg[ul][d];
            #pragma unroll
            for (int j = 0; j < 4; ++j) {
                f32x4 wv = *(const f32x4*)&Wl[d][o0 + 4 * j];
                acc[j] += wv * av;
            }
        }
        float* dst = out + (size_t)(u0 + ul) * OUT_N + o0;
        #pragma unroll
        for (int j = 0; j < 4; ++j)
            *(f32x4*)(dst + 4 * j) = acc[j];
    }
}

// ---------------------------------------------------------------------------
extern "C" void kernel_launch(void* const* d_in, const int* in_sizes, int n_in,
                              void* d_out, int out_size, void* d_ws, size_t ws_size,
                              hipStream_t stream)
{
    const float* user_emb = (const float*)d_in[0];
    const float* item_emb = (const float*)d_in[1];
    const float* attw     = (const float*)d_in[2];
    const int*   adj      = (const int*)d_in[3];
    float* out = (float*)d_out;

    // ws layout: wsO | wsL | itemH | itemTt
    float*          wsO    = (float*)d_ws;
    float*          wsL    = wsO + (size_t)NCH * U_N * D_N;
    _Float16*       itemH  = (_Float16*)(wsL + (size_t)NCH * U_N);
    unsigned short* itemTt = (unsigned short*)(itemH + (size_t)I_N * D_N);

    prep_items<<<dim3(I_N / 256), 256, 0, stream>>>(item_emb, itemH, itemTt);
    atten_main<<<dim3(NCH, U_N / 64), 256, 0, stream>>>(user_emb, itemH, itemTt, adj,
                                                        wsO, wsL);
    atten_combine<<<dim3(U_N / 64), 256, 0, stream>>>(wsO, wsL, attw, out, NCH);
}

// Round 7
// 713.883 us; speedup vs baseline: 1.7694x; 1.0138x over previous
//
#include <hip/hip_runtime.h>
#include <hip/hip_bf16.h>
#include <math.h>

#define U_N   8192
#define I_N   16384
#define D_N   64
#define OUT_N 64
#define BN    32           // items per iteration tile
#define NCH   8            // item chunks (split-K)
#define ITERS 64           // (I_N/NCH)/BN
#define VN_ST 72           // Vn stride (halves): 144B rows, b128 reads 2-way-free
#define VT_ST 40           // Vt stride (halves): 80B rows, b128-aligned, 2-way-free
#define PL_ST 40           // P round-trip stride (halves), 80B rows

typedef _Float16 half8  __attribute__((ext_vector_type(8)));
typedef short    bf16x8 __attribute__((ext_vector_type(8)));
typedef short    bf16x4 __attribute__((ext_vector_type(4)));
typedef float    f32x4  __attribute__((ext_vector_type(4)));
typedef int      int4v  __attribute__((ext_vector_type(4)));

static __device__ __forceinline__ unsigned short f2bf(float f) {
    union { __hip_bfloat16 h; unsigned short u; } cv;
    cv.h = __float2bfloat16(f);
    return cv.u;
}
// Barrier WITHOUT vmcnt drain: LDS-only wait; global prefetches stay in flight.
static __device__ __forceinline__ void bar() {
    asm volatile("s_waitcnt lgkmcnt(0)\n\ts_barrier" ::: "memory");
}

// ---------------------------------------------------------------------------
// Prep: item_emb fp32 -> itemH f16 [item][dim] and itemTt bf16 tiled
// transpose [item>>5][dim][item&31] (staging becomes contiguous 16B copies).
// ---------------------------------------------------------------------------
__global__ __launch_bounds__(256)
void prep_items(const float* __restrict__ item,
                _Float16* __restrict__ itemH,
                unsigned short* __restrict__ itemTt)
{
    const int i = blockIdx.x * 256 + threadIdx.x;
    const float* src = item + (size_t)i * D_N;
    f32x4 v[16];
    #pragma unroll
    for (int j = 0; j < 16; ++j) v[j] = *(const f32x4*)(src + 4 * j);

    #pragma unroll
    for (int j = 0; j < 8; ++j) {
        half8 h;
        #pragma unroll
        for (int k = 0; k < 4; ++k) { h[k] = (_Float16)v[2*j][k]; h[4+k] = (_Float16)v[2*j+1][k]; }
        *(half8*)&itemH[(size_t)i * D_N + 8 * j] = h;
    }
    const size_t tb = (size_t)(i >> 5) * (D_N * 32) + (i & 31);
    #pragma unroll
    for (int d = 0; d < 64; ++d)
        itemTt[tb + (size_t)d * 32] = f2bf(v[d >> 2][d & 3]);
}

// ---------------------------------------------------------------------------
// Named-register pipeline state (arrays/structs/lambdas demote to scratch ->
// ~1 GB HBM scratch traffic; r3/r4 lesson).
// ---------------------------------------------------------------------------
#define DECL_SET(S) \
    int4v adj##S##a, adj##S##b; \
    half8 vn##S; bf16x8 vt##S;

// lane (q,c): adj row urow0+c, items it*32 + 4q..4q+3 (a) and +16 (b)
#define LOAD_ADJ(S, tidx) do { \
    const size_t o_ = (size_t)(tidx) * BN; \
    adj##S##a = *(const int4v*)&adjq[o_];      \
    adj##S##b = *(const int4v*)&adjq[o_ + 16]; \
} while (0)

#define LOAD_TILE(S, tidx) do { \
    const size_t o_ = (size_t)(tidx) * BN; \
    vn##S = *(const half8*)&itemH[(ibase0 + o_ + (t >> 3)) * D_N + (t & 7) * 8]; \
    vt##S = *(const bf16x8*)&itemTt[((ibase0 + o_) >> 5) * (D_N * 32) \
                                    + (size_t)(t >> 2) * 32 + (t & 3) * 8]; \
} while (0)

#define COMMIT(S, bufw) do { \
    *(half8*)&Vn[bufw][(t >> 3) * VN_ST + (t & 7) * 8] = vn##S; \
    *(bf16x8*)&Vt[bufw][(t >> 2) * VT_ST + (t & 3) * 8] = vt##S; \
} while (0)

// per-lane 8-bit masks (extracted BEFORE the adj regs get reloaded)
#define MASKS(S, ma, mb) \
    const unsigned ma = ((adj##S##a[0] != 0) ? 1u : 0u) | ((adj##S##a[1] != 0) ? 2u : 0u) | \
                        ((adj##S##a[2] != 0) ? 4u : 0u) | ((adj##S##a[3] != 0) ? 8u : 0u); \
    const unsigned mb = ((adj##S##b[0] != 0) ? 1u : 0u) | ((adj##S##b[1] != 0) ? 2u : 0u) | \
                        ((adj##S##b[2] != 0) ? 4u : 0u) | ((adj##S##b[3] != 0) ? 8u : 0u);

// S^T = Item * User^T: A = item frags (Vn), B = ufrag. C-layout: lane (q,c)
// holds S^T[item=ig*16+4q+r][user=c] -> all 8 values belong to user row c.
#define COMPUTE_REST(ma, mb, bufr) do { \
    half8 a00 = *(const half8*)&Vn[bufr][(c)      * VN_ST      + q * 8]; \
    half8 a01 = *(const half8*)&Vn[bufr][(c)      * VN_ST + 32 + q * 8]; \
    half8 a10 = *(const half8*)&Vn[bufr][(16 + c) * VN_ST      + q * 8]; \
    half8 a11 = *(const half8*)&Vn[bufr][(16 + c) * VN_ST + 32 + q * 8]; \
    bf16x8 v0 = *(const bf16x8*)&Vt[bufr][(c)      * VT_ST + q * 8]; \
    bf16x8 v1 = *(const bf16x8*)&Vt[bufr][(16 + c) * VT_ST + q * 8]; \
    bf16x8 v2 = *(const bf16x8*)&Vt[bufr][(32 + c) * VT_ST + q * 8]; \
    bf16x8 v3 = *(const bf16x8*)&Vt[bufr][(48 + c) * VT_ST + q * 8]; \
    f32x4 T0 = (f32x4){0.f,0.f,0.f,0.f}; \
    f32x4 T1 = (f32x4){0.f,0.f,0.f,0.f}; \
    T0 = __builtin_amdgcn_mfma_f32_16x16x32_f16(a00, ufrag0, T0, 0, 0, 0); \
    T0 = __builtin_amdgcn_mfma_f32_16x16x32_f16(a01, ufrag1, T0, 0, 0, 0); \
    T1 = __builtin_amdgcn_mfma_f32_16x16x32_f16(a10, ufrag0, T1, 0, 0, 0); \
    T1 = __builtin_amdgcn_mfma_f32_16x16x32_f16(a11, ufrag1, T1, 0, 0, 0); \
    bf16x4 p0, p1; \
    float e_; \
    e_ = __expf(((ma) & 1u) ? T0[0] : 0.0f); p0[0] = (short)f2bf(e_); lc += e_; \
    e_ = __expf(((ma) & 2u) ? T0[1] : 0.0f); p0[1] = (short)f2bf(e_); lc += e_; \
    e_ = __expf(((ma) & 4u) ? T0[2] : 0.0f); p0[2] = (short)f2bf(e_); lc += e_; \
    e_ = __expf(((ma) & 8u) ? T0[3] : 0.0f); p0[3] = (short)f2bf(e_); lc += e_; \
    e_ = __expf(((mb) & 1u) ? T1[0] : 0.0f); p1[0] = (short)f2bf(e_); lc += e_; \
    e_ = __expf(((mb) & 2u) ? T1[1] : 0.0f); p1[1] = (short)f2bf(e_); lc += e_; \
    e_ = __expf(((mb) & 4u) ? T1[2] : 0.0f); p1[2] = (short)f2bf(e_); lc += e_; \
    e_ = __expf(((mb) & 8u) ? T1[3] : 0.0f); p1[3] = (short)f2bf(e_); lc += e_; \
    *(bf16x4*)&plw[c * PL_ST + 4 * q]      = p0; \
    *(bf16x4*)&plw[c * PL_ST + 16 + 4 * q] = p1; \
    bf16x8 pf = *(const bf16x8*)&plw[c * PL_ST + q * 8]; \
    O0 = __builtin_amdgcn_mfma_f32_16x16x32_bf16(pf, v0, O0, 0, 0, 0); \
    O1 = __builtin_amdgcn_mfma_f32_16x16x32_bf16(pf, v1, O1, 0, 0, 0); \
    O2 = __builtin_amdgcn_mfma_f32_16x16x32_bf16(pf, v2, O2, 0, 0, 0); \
    O3 = __builtin_amdgcn_mfma_f32_16x16x32_bf16(pf, v3, O3, 0, 0, 0); \
} while (0)

// ---------------------------------------------------------------------------
// Main: cooperative ping-pong LDS staging, one LDS-only barrier/iter, global
// prefetches in flight across barriers. Tile j: loaded j-3..j-2, committed
// j-1, consumed j. adj consumed from named regs (dist-2).
// ---------------------------------------------------------------------------
__global__ __launch_bounds__(256, 3)
void atten_main(const float* __restrict__ user_emb,
                const _Float16* __restrict__ itemH,
                const unsigned short* __restrict__ itemTt,
                const int*   __restrict__ adj,
                float* __restrict__ wsO,
                float* __restrict__ wsL)
{
    __shared__ _Float16 Vn[2][BN * VN_ST];         // [item][dim] f16   (S^T A-frags)
    __shared__ short    Vt[2][D_N * VT_ST];        // [dim][item] bf16  (PV B-frags)
    __shared__ unsigned short Pl[4][16 * PL_ST];   // per-wave P round-trip

    const int ch   = blockIdx.x;
    const int ub   = blockIdx.y;
    const int t    = threadIdx.x;
    const int w    = t >> 6;
    const int lane = t & 63;
    const int c    = lane & 15;
    const int q    = lane >> 4;

    const int    urow0  = ub * 64 + w * 16;
    const size_t ibase0 = (size_t)ch * (I_N / NCH);

    unsigned short* plw = &Pl[w][0];

    // persistent user fragments (f16); same registers serve as the MFMA
    // B-operand (B[k=ks*32+q*8+j][n=c]) for the transposed S matmul.
    half8 ufrag0, ufrag1;
    {
        const float* up = user_emb + (size_t)(urow0 + c) * D_N + q * 8;
        f32x4 a0 = *(const f32x4*)(up);
        f32x4 b0 = *(const f32x4*)(up + 4);
        f32x4 a1 = *(const f32x4*)(up + 32);
        f32x4 b1 = *(const f32x4*)(up + 36);
        #pragma unroll
        for (int j = 0; j < 4; ++j) {
            ufrag0[j] = (_Float16)a0[j]; ufrag0[4 + j] = (_Float16)b0[j];
            ufrag1[j] = (_Float16)a1[j]; ufrag1[4 + j] = (_Float16)b1[j];
        }
    }

    f32x4 O0 = (f32x4){0.f,0.f,0.f,0.f};
    f32x4 O1 = O0, O2 = O0, O3 = O0;
    float lc = 0.f;                       // softmax denom partial for user c

    // adj base: row urow0+c, item offset 4q (dwordx4 covers items 4q..4q+3)
    const int* adjq = adj + (size_t)(urow0 + c) * I_N + ibase0 + 4 * q;

    DECL_SET(A)
    DECL_SET(B)

    LOAD_TILE(A, 0); LOAD_ADJ(A, 0);
    LOAD_TILE(B, 1); LOAD_ADJ(B, 1);
    COMMIT(A, 0);
    LOAD_TILE(A, 2);
    bar();

    for (int k = 0; k < ITERS; k += 2) {
        {   // iter k: consume buf0 + adjA; commit B->buf1; reload A-side
            MASKS(A, ma, mb)
            COMMIT(B, 1);
            const int ia = (k + 2 < ITERS) ? k + 2 : ITERS - 1;
            const int iv = (k + 3 < ITERS) ? k + 3 : ITERS - 1;
            LOAD_ADJ(A, ia);
            LOAD_TILE(B, iv);
            COMPUTE_REST(ma, mb, 0);
            bar();
        }
        {   // iter k+1: consume buf1 + adjB; commit A->buf0; reload B-side
            MASKS(B, ma, mb)
            COMMIT(A, 0);
            const int ia = (k + 3 < ITERS) ? k + 3 : ITERS - 1;
            const int iv = (k + 4 < ITERS) ? k + 4 : ITERS - 1;
            LOAD_ADJ(B, ia);
            LOAD_TILE(A, iv);
            COMPUTE_REST(ma, mb, 1);
            bar();
        }
    }

    // l lives per-lane for user c: reduce across the 4 quads (lanes c+16q)
    lc += __shfl_xor(lc, 16);
    lc += __shfl_xor(lc, 32);

    // write chunk partials (O C-layout: lane (q,c): O[user 4q+r][dim 16nt+c])
    {
        float* d0 = wsO + ((size_t)ch * U_N + urow0 + 4 * q + 0) * D_N;
        float* d1 = wsO + ((size_t)ch * U_N + urow0 + 4 * q + 1) * D_N;
        float* d2 = wsO + ((size_t)ch * U_N + urow0 + 4 * q + 2) * D_N;
        float* d3 = wsO + ((size_t)ch * U_N + urow0 + 4 * q + 3) * D_N;
        d0[c] = O0[0]; d0[16 + c] = O1[0]; d0[32 + c] = O2[0]; d0[48 + c] = O3[0];
        d1[c] = O0[1]; d1[16 + c] = O1[1]; d1[32 + c] = O2[1]; d1[48 + c] = O3[1];
        d2[c] = O0[2]; d2[16 + c] = O1[2]; d2[32 + c] = O2[2]; d2[48 + c] = O3[2];
        d3[c] = O0[3]; d3[16 + c] = O1[3]; d3[32 + c] = O2[3]; d3[48 + c] = O3[3];
    }
    if (q == 0)
        wsL[(size_t)ch * U_N + urow0 + c] = lc;
}

// ---------------------------------------------------------------------------
// Combine: sum chunk partials, normalize, project by attention_weight.
// ---------------------------------------------------------------------------
__global__ __launch_bounds__(256)
void atten_combine(const float* __restrict__ wsO,
                   const float* __restrict__ wsL,
                   const float* __restrict__ attw,
                   float* __restrict__ out,
                   int nch)
{
    __shared__ float inv[64];
    __shared__ float agg[64][68];
    __shared__ float Wl[64][68];

    const int t  = threadIdx.x;
    const int u0 = blockIdx.x * 64;

    {
        const int d = t >> 2, o0 = (t & 3) * 16;
        const float* src = attw + d * OUT_N + o0;
        #pragma unroll
        for (int j = 0; j < 4; ++j)
            *(f32x4*)&Wl[d][o0 + 4 * j] = *(const f32x4*)(src + 4 * j);
    }
    if (t < 64) {
        float L = 0.f;
        for (int cc = 0; cc < nch; ++cc) L += wsL[(size_t)cc * U_N + u0 + t];
        inv[t] = 1.0f / L;
    }
    __syncthreads();

    {
        const int ul = t >> 2, d0 = (t & 3) * 16;
        const int u = u0 + ul;
        f32x4 a4[4];
        #pragma unroll
        for (int j = 0; j < 4; ++j) a4[j] = (f32x4){0.f, 0.f, 0.f, 0.f};
        for (int cc = 0; cc < nch; ++cc) {
            const float* src = wsO + ((size_t)cc * U_N + u) * D_N + d0;
            #pragma unroll
            for (int j = 0; j < 4; ++j) a4[j] += *(const f32x4*)(src + 4 * j);
        }
        const float s = inv[ul];
        #pragma unroll
        for (int j = 0; j < 4; ++j)
            *(f32x4*)&agg[ul][d0 + 4 * j] = a4[j] * s;
    }
    __syncthreads();

    {
        const int ul = t >> 2, o0 = (t & 3) * 16;
        f32x4 acc[4];
        #pragma unroll
        for (int j = 0; j < 4; ++j) acc[j] = (f32x4){0.f, 0.f, 0.f, 0.f};
        for (int d = 0; d < 64; ++d) {
            const float av = agg[ul][d];
            #pragma unroll
            for (int j = 0; j < 4; ++j) {
                f32x4 wv = *(const f32x4*)&Wl[d][o0 + 4 * j];
                acc[j] += wv * av;
            }
        }
        float* dst = out + (size_t)(u0 + ul) * OUT_N + o0;
        #pragma unroll
        for (int j = 0; j < 4; ++j)
            *(f32x4*)(dst + 4 * j) = acc[j];
    }
}

// ---------------------------------------------------------------------------
extern "C" void kernel_launch(void* const* d_in, const int* in_sizes, int n_in,
                              void* d_out, int out_size, void* d_ws, size_t ws_size,
                              hipStream_t stream)
{
    const float* user_emb = (const float*)d_in[0];
    const float* item_emb = (const float*)d_in[1];
    const float* attw     = (const float*)d_in[2];
    const int*   adj      = (const int*)d_in[3];
    float* out = (float*)d_out;

    // ws layout: wsO | wsL | itemH | itemTt
    float*          wsO    = (float*)d_ws;
    float*          wsL    = wsO + (size_t)NCH * U_N * D_N;
    _Float16*       itemH  = (_Float16*)(wsL + (size_t)NCH * U_N);
    unsigned short* itemTt = (unsigned short*)(itemH + (size_t)I_N * D_N);

    prep_items<<<dim3(I_N / 256), 256, 0, stream>>>(item_emb, itemH, itemTt);
    atten_main<<<dim3(NCH, U_N / 64), 256, 0, stream>>>(user_emb, itemH, itemTt, adj,
                                                        wsO, wsL);
    atten_combine<<<dim3(U_N / 64), 256, 0, stream>>>(wsO, wsL, attw, out, NCH);
}